// Round 9
// baseline (2944.290 us; speedup 1.0000x reference)
//
#include <hip/hip_runtime.h>
#include <hip/hip_bf16.h>
#include <cstddef>

typedef __hip_bfloat16 bf16;

// ---------------- problem constants ----------------
#define D_MODEL 1048
#define P_DIM   1048
#define NLAYER  3
#define BSZ     4
#define LSEQ    4096
#define BL      (BSZ*LSEQ)                 // 16384 rows
#define BLD     ((size_t)BL*D_MODEL)       // unpadded elements
#define KP      1056                       // padded K / row stride (33*32)
#define NP      1152                       // padded N for weights (9*128)
#define BLA     ((size_t)BL*KP)            // padded activation elements
#define NPKP    ((size_t)NP*KP)            // padded weight elements
#define NKT     33                         // K slices of 32

// scan chunking
#define NC      64
#define CL      (LSEQ/NC)                  // 64
#define NSCAN   (BSZ*NC*P_DIM)

typedef __attribute__((ext_vector_type(8))) short short8;
typedef __attribute__((ext_vector_type(4))) float f32x4;

#define TM 128
#define TN 128
#define TK 32
#define TILE_SH (TM*TK)                    // 4096 shorts = 8 KB per buffer
#define NGEMM   ((BL/TM)*(NP/TN))          // 1152 blocks

__device__ __forceinline__ float gelu_f(float x) {
    return 0.5f * x * (1.f + erff(x * 0.70710678118654752f));
}

// XCD-aware mapping (1152 blocks): 9 consecutive blocks on one XCD share an
// A m-tile (xcd = blockId % 8 round-robin).
__device__ __forceinline__ void tile_coords(int id, int& m0, int& n0) {
    int xcd  = id & 7;
    int slot = id >> 3;          // 0..143
    int xg   = slot / 9;         // 0..15
    int j    = slot - xg*9;      // 0..8
    m0 = (xg*8 + xcd) * TM;
    n0 = j * TN;
}

// ---------------- staging: one 128x32 bf16 tile via global_load_lds --------
__device__ __forceinline__ void stage_tile(
    const bf16* __restrict__ src, int row0, int k0, short* lds, int tid)
{
#pragma unroll
    for (int c = 0; c < 2; ++c) {
        int chunk = tid + 256*c;          // 0..511
        int r = chunk >> 2;
        int col = (chunk & 3) * 8;
        __builtin_amdgcn_global_load_lds(
            (const __attribute__((address_space(1))) void*)(src + (size_t)(row0 + r)*KP + k0 + col),
            (__attribute__((address_space(3))) void*)(lds + chunk*8), 16, 0, 0);
    }
}

// ---------------- MFMA sub-steps (one TK=32 slice) ----------------
__device__ __forceinline__ void mfma_step1(
    const short* As, const short* Ws, f32x4 (&acc)[4][4],
    int wm, int wn, int row_in, int quad)
{
    short8 a[4], b[4];
#pragma unroll
    for (int i = 0; i < 4; ++i) {
        a[i] = *(const short8*)&As[(wm + i*16 + row_in)*TK + quad*8];
        b[i] = *(const short8*)&Ws[(wn + i*16 + row_in)*TK + quad*8];
    }
#pragma unroll
    for (int i = 0; i < 4; ++i)
#pragma unroll
        for (int j = 0; j < 4; ++j)
            acc[i][j] = __builtin_amdgcn_mfma_f32_16x16x32_bf16(a[i], b[j], acc[i][j], 0, 0, 0);
}

__device__ __forceinline__ void mfma_step2(
    const short* As, const short* W0s, const short* W1s,
    f32x4 (&acc0)[4][4], f32x4 (&acc1)[4][4],
    int wm, int wn, int row_in, int quad)
{
    short8 a[4], b0[4], b1[4];
#pragma unroll
    for (int i = 0; i < 4; ++i) {
        a[i]  = *(const short8*)&As [(wm + i*16 + row_in)*TK + quad*8];
        b0[i] = *(const short8*)&W0s[(wn + i*16 + row_in)*TK + quad*8];
        b1[i] = *(const short8*)&W1s[(wn + i*16 + row_in)*TK + quad*8];
    }
#pragma unroll
    for (int i = 0; i < 4; ++i)
#pragma unroll
        for (int j = 0; j < 4; ++j) {
            acc0[i][j] = __builtin_amdgcn_mfma_f32_16x16x32_bf16(a[i], b0[j], acc0[i][j], 0, 0, 0);
            acc1[i][j] = __builtin_amdgcn_mfma_f32_16x16x32_bf16(a[i], b1[j], acc1[i][j], 0, 0, 0);
        }
}

// ---------------- dual-output GEMM (double-buffered LDS) --------------------
// MODE 0: store both (pads zeroed).  MODE 1: O0 = acc0 * gelu(acc1).
template <int MODE>
__global__ __launch_bounds__(256) void gemm2o_k(
    const bf16* __restrict__ A, const bf16* __restrict__ W0,
    const bf16* __restrict__ W1,
    bf16* __restrict__ O0, bf16* __restrict__ O1, int N)
{
    __shared__ short As[2][TILE_SH];
    __shared__ short W0s[2][TILE_SH];
    __shared__ short W1s[2][TILE_SH];
    const int tid  = threadIdx.x;
    int m0, n0;
    tile_coords(blockIdx.x, m0, n0);
    const int wave = tid >> 6, lane = tid & 63;
    const int wm = (wave >> 1) * 64, wn = (wave & 1) * 64;
    const int row_in = lane & 15, quad = lane >> 4;

    f32x4 acc0[4][4] = {};
    f32x4 acc1[4][4] = {};

    // prologue: stage slice 0 into buf 0
    stage_tile(A,  m0, 0, As[0],  tid);
    stage_tile(W0, n0, 0, W0s[0], tid);
    stage_tile(W1, n0, 0, W1s[0], tid);
    int cur = 0;
    for (int kt = 0; kt < NKT; ++kt) {
        __syncthreads();                       // buf[cur] staged (vmcnt drained)
        if (kt + 1 < NKT) {                    // prefetch next into other buf
            int k1 = (kt + 1) * TK;
            stage_tile(A,  m0, k1, As[cur^1],  tid);
            stage_tile(W0, n0, k1, W0s[cur^1], tid);
            stage_tile(W1, n0, k1, W1s[cur^1], tid);
        }
        mfma_step2(As[cur], W0s[cur], W1s[cur], acc0, acc1, wm, wn, row_in, quad);
        cur ^= 1;
    }

#pragma unroll
    for (int i = 0; i < 4; ++i) {
#pragma unroll
        for (int j = 0; j < 4; ++j) {
            int n = n0 + wn + j*16 + row_in;
#pragma unroll
            for (int r = 0; r < 4; ++r) {
                int m = m0 + wm + i*16 + quad*4 + r;
                size_t o = (size_t)m*KP + n;
                if (MODE == 0) {
                    if (n < N)        { O0[o] = __float2bfloat16(acc0[i][j][r]);
                                        O1[o] = __float2bfloat16(acc1[i][j][r]); }
                    else if (n < KP)  { O0[o] = __float2bfloat16(0.f);
                                        O1[o] = __float2bfloat16(0.f); }
                } else {
                    if (n < N)        O0[o] = __float2bfloat16(acc0[i][j][r] * gelu_f(acc1[i][j][r]));
                    else if (n < KP)  O0[o] = __float2bfloat16(0.f);
                }
            }
        }
    }
}

// ---------------- dual-input GEMM + sepi epilogue (double-buffered) --------
// acc = A0@W0^T + A1@W1^T;  O = gelu(acc + dv[n]*fx) + fx   (pads zeroed)
__global__ __launch_bounds__(256) void gemmC_k(
    const bf16* __restrict__ A0, const bf16* __restrict__ W0,
    const bf16* __restrict__ A1, const bf16* __restrict__ W1,
    const bf16* __restrict__ fx, const float* __restrict__ dv,
    bf16* __restrict__ O, int N)
{
    __shared__ short As[2][TILE_SH];
    __shared__ short Ws[2][TILE_SH];
    const int tid  = threadIdx.x;
    int m0, n0;
    tile_coords(blockIdx.x, m0, n0);
    const int wave = tid >> 6, lane = tid & 63;
    const int wm = (wave >> 1) * 64, wn = (wave & 1) * 64;
    const int row_in = lane & 15, quad = lane >> 4;

    f32x4 acc[4][4] = {};

    // 66 slices: s -> pair = s/NKT, k = (s%NKT)*TK
    stage_tile(A0, m0, 0, As[0], tid);
    stage_tile(W0, n0, 0, Ws[0], tid);
    int cur = 0;
    for (int s = 0; s < 2*NKT; ++s) {
        __syncthreads();
        if (s + 1 < 2*NKT) {
            int sn = s + 1;
            const bf16* An = (sn < NKT) ? A0 : A1;
            const bf16* Wn = (sn < NKT) ? W0 : W1;
            int k1 = (sn < NKT ? sn : sn - NKT) * TK;
            stage_tile(An, m0, k1, As[cur^1], tid);
            stage_tile(Wn, n0, k1, Ws[cur^1], tid);
        }
        mfma_step1(As[cur], Ws[cur], acc, wm, wn, row_in, quad);
        cur ^= 1;
    }

#pragma unroll
    for (int i = 0; i < 4; ++i) {
#pragma unroll
        for (int j = 0; j < 4; ++j) {
            int n = n0 + wn + j*16 + row_in;
#pragma unroll
            for (int r = 0; r < 4; ++r) {
                int m = m0 + wm + i*16 + quad*4 + r;
                size_t o = (size_t)m*KP + n;
                if (n < N) {
                    float f = __bfloat162float(fx[o]);
                    float t = acc[i][j][r] + dv[n]*f;
                    O[o] = __float2bfloat16(gelu_f(t) + f);
                } else if (n < KP) {
                    O[o] = __float2bfloat16(0.f);
                }
            }
        }
    }
}

// ---------------- single GEMM + residual epilogue (double-buffered) --------
__global__ __launch_bounds__(256) void gemmD_k(
    const bf16* __restrict__ A, const bf16* __restrict__ W,
    const bf16* __restrict__ fy, float* __restrict__ h, int N)
{
    __shared__ short As[2][TILE_SH];
    __shared__ short Ws[2][TILE_SH];
    const int tid  = threadIdx.x;
    int m0, n0;
    tile_coords(blockIdx.x, m0, n0);
    const int wave = tid >> 6, lane = tid & 63;
    const int wm = (wave >> 1) * 64, wn = (wave & 1) * 64;
    const int row_in = lane & 15, quad = lane >> 4;

    f32x4 acc[4][4] = {};

    stage_tile(A, m0, 0, As[0], tid);
    stage_tile(W, n0, 0, Ws[0], tid);
    int cur = 0;
    for (int kt = 0; kt < NKT; ++kt) {
        __syncthreads();
        if (kt + 1 < NKT) {
            int k1 = (kt + 1) * TK;
            stage_tile(A, m0, k1, As[cur^1], tid);
            stage_tile(W, n0, k1, Ws[cur^1], tid);
        }
        mfma_step1(As[cur], Ws[cur], acc, wm, wn, row_in, quad);
        cur ^= 1;
    }

#pragma unroll
    for (int i = 0; i < 4; ++i) {
#pragma unroll
        for (int j = 0; j < 4; ++j) {
            int n = n0 + wn + j*16 + row_in;
            if (n >= N) continue;
#pragma unroll
            for (int r = 0; r < 4; ++r) {
                int m = m0 + wm + i*16 + quad*4 + r;
                float f = __bfloat162float(fy[(size_t)m*KP + n]);
                h[(size_t)m*D_MODEL + n] += acc[i][j][r] + f;
            }
        }
    }
}

// ---------------- batched weight conversion (5x 1048x1048 fp32 -> bf16) ----
__global__ __launch_bounds__(256) void convw5_k(
    const float* __restrict__ s0, const float* __restrict__ s1,
    const float* __restrict__ s2, const float* __restrict__ s3,
    const float* __restrict__ s4, bf16* __restrict__ dst)
{
    size_t i = (size_t)blockIdx.x*256 + threadIdx.x;
    if (i >= NPKP) return;
    int z = blockIdx.z;
    const float* src = (z == 0) ? s0 : (z == 1) ? s1 : (z == 2) ? s2 : (z == 3) ? s3 : s4;
    float scale = (z == 1) ? -1.f : 1.f;
    int n = (int)(i / KP), k = (int)(i - (size_t)n*KP);
    float v = (n < D_MODEL && k < D_MODEL) ? scale*src[(size_t)n*D_MODEL + k] : 0.f;
    dst[(size_t)z*NPKP + i] = __float2bfloat16(v);
}

// ---------------- reductions ----------------
__device__ __forceinline__ float2 block_reduce2(float a, float b) {
    __syncthreads();   // safe for repeated calls (shared reuse)
    for (int off = 32; off; off >>= 1) {
        a += __shfl_down(a, off, 64);
        b += __shfl_down(b, off, 64);
    }
    __shared__ float sa[4], sb[4];
    int lane = threadIdx.x & 63, wv = threadIdx.x >> 6;
    if (lane == 0) { sa[wv] = a; sb[wv] = b; }
    __syncthreads();
    if (threadIdx.x == 0) {
        sa[0] = sa[0]+sa[1]+sa[2]+sa[3];
        sb[0] = sb[0]+sb[1]+sb[2]+sb[3];
    }
    __syncthreads();
    return make_float2(sa[0], sb[0]);
}

// ---------------- encode ----------------
__global__ __launch_bounds__(256) void encode_k(
    const float* __restrict__ x, const float* __restrict__ ew,
    const float* __restrict__ eb, float* __restrict__ h)
{
    size_t i = (size_t)blockIdx.x*256 + threadIdx.x;
    if (i >= BLD) return;
    int d = (int)(i % D_MODEL);
    size_t bl = i / D_MODEL;
    h[i] = x[bl]*ew[d] + eb[d];
}

// ---------------- fused double layernorm: fx = LN(LN(h,w1,b1),w2,b2) -------
__global__ __launch_bounds__(256) void ln2x_k(
    const float* __restrict__ x,
    const float* __restrict__ w1, const float* __restrict__ bb1,
    const float* __restrict__ w2, const float* __restrict__ bb2,
    bf16* __restrict__ y)
{
    const size_t row = blockIdx.x;
    const float* xr = x + row * D_MODEL;
    float v[5];
    float s = 0.f, ss = 0.f;
    int i = 0;
    for (int d = threadIdx.x; d < KP; d += 256, ++i) {
        float t = (d < D_MODEL) ? xr[d] : 0.f;
        v[i] = t; s += t; ss += t*t;
    }
    float2 r = block_reduce2(s, ss);
    float mu  = r.x * (1.f/D_MODEL);
    float var = r.y * (1.f/D_MODEL) - mu*mu;
    float inv = rsqrtf(var + 1e-5f);
    s = 0.f; ss = 0.f; i = 0;
    for (int d = threadIdx.x; d < KP; d += 256, ++i) {
        float z = (d < D_MODEL) ? (v[i]-mu)*inv*w1[d] + bb1[d] : 0.f;
        v[i] = z; s += z; ss += z*z;
    }
    r = block_reduce2(s, ss);
    mu  = r.x * (1.f/D_MODEL);
    var = r.y * (1.f/D_MODEL) - mu*mu;
    inv = rsqrtf(var + 1e-5f);
    bf16* yr = y + row * KP;
    i = 0;
    for (int d = threadIdx.x; d < KP; d += 256, ++i) {
        float o = (d < D_MODEL) ? (v[i]-mu)*inv*w2[d] + bb2[d] : 0.f;
        yr[d] = __float2bfloat16(o);
    }
}

// ---------------- single layernorm (bf16 in stride KP) ----------------
__global__ __launch_bounds__(256) void ln_k(
    const bf16* __restrict__ x, const float* __restrict__ w,
    const float* __restrict__ b, bf16* __restrict__ y)
{
    const size_t row = blockIdx.x;
    const bf16* xr = x + row * KP;
    float v[5];
    float s = 0.f, ss = 0.f;
    int i = 0;
    for (int d = threadIdx.x; d < KP; d += 256, ++i) {
        float t = (d < D_MODEL) ? __bfloat162float(xr[d]) : 0.f;
        v[i] = t; s += t; ss += t*t;
    }
    float2 r = block_reduce2(s, ss);
    float mu  = r.x * (1.f/D_MODEL);
    float var = r.y * (1.f/D_MODEL) - mu*mu;
    float inv = rsqrtf(var + 1e-5f);
    bf16* yr = y + row * KP;
    i = 0;
    for (int d = threadIdx.x; d < KP; d += 256, ++i) {
        float o = (d < D_MODEL) ? (v[i]-mu)*inv*w[d] + b[d] : 0.f;
        yr[d] = __float2bfloat16(o);
    }
}

// ---------------- per-layer SSM precompute (padded Bbar) ----------------
__global__ __launch_bounds__(256) void prep_k(
    const float* __restrict__ lam_re, const float* __restrict__ lam_im,
    const float* __restrict__ log_step,
    const float* __restrict__ B_re, const float* __restrict__ B_im,
    bf16* __restrict__ bbar_re, bf16* __restrict__ bbar_im,
    float* __restrict__ abar)
{
    size_t idx = (size_t)blockIdx.x*256 + threadIdx.x;
    if (idx >= NPKP) return;
    int p = (int)(idx / KP);
    int d = (int)(idx - (size_t)p*KP);
    if (p >= P_DIM || d >= D_MODEL) {
        bbar_re[idx] = __float2bfloat16(0.f);
        bbar_im[idx] = __float2bfloat16(0.f);
        return;
    }
    float lr = lam_re[p], li = lam_im[p];
    float st = expf(log_step[p]);
    float er = expf(lr*st);
    float ar = er * cosf(li*st);
    float ai = er * sinf(li*st);
    if (d == 0) { abar[p] = ar; abar[P_DIM + p] = ai; }
    float den = lr*lr + li*li;
    float xr = ar - 1.f, xi = ai;
    float cr = (xr*lr + xi*li) / den;
    float ci = (xi*lr - xr*li) / den;
    float br = B_re[(size_t)p*D_MODEL + d], bi = B_im[(size_t)p*D_MODEL + d];
    bbar_re[idx] = __float2bfloat16(cr*br - ci*bi);
    bbar_im[idx] = __float2bfloat16(cr*bi + ci*br);
}

// ---------------- chunked parallel scan ----------------
__global__ __launch_bounds__(256) void scan_partial_k(
    const bf16* __restrict__ ur, const bf16* __restrict__ ui,
    const float* __restrict__ abar,
    float* __restrict__ sum_re, float* __restrict__ sum_im)
{
    int idx = blockIdx.x*256 + threadIdx.x;
    if (idx >= NSCAN) return;
    int p = idx % P_DIM;
    int rest = idx / P_DIM;
    int c = rest % NC, b = rest / NC;
    float ar = abar[p], ai = abar[P_DIM + p];
    size_t base = ((size_t)b*LSEQ + (size_t)c*CL)*KP + p;
    float sre = 0.f, sim = 0.f;
    for (int i = 0; i < CL; ++i) {
        size_t o = base + (size_t)i*KP;
        float br = __bfloat162float(ur[o]);
        float bi = __bfloat162float(ui[o]);
        float nr = fmaf(ar, sre, fmaf(-ai, sim, br));
        float ni = fmaf(ar, sim, fmaf( ai, sre, bi));
        sre = nr; sim = ni;
    }
    sum_re[idx] = sre; sum_im[idx] = sim;
}

__global__ __launch_bounds__(256) void scan_carry_k(
    const float* __restrict__ sum_re, const float* __restrict__ sum_im,
    const float* __restrict__ abar,
    float* __restrict__ car_re, float* __restrict__ car_im)
{
    int idx = blockIdx.x*256 + threadIdx.x;
    if (idx >= BSZ*P_DIM) return;
    int p = idx % P_DIM, b = idx / P_DIM;
    float cr = abar[p], ci = abar[P_DIM + p];
#pragma unroll
    for (int s = 0; s < 6; ++s) {
        float nr = cr*cr - ci*ci;
        float ni = 2.f*cr*ci;
        cr = nr; ci = ni;
    }
    float xre = 0.f, xim = 0.f;
    size_t base = (size_t)b*NC*P_DIM + p;
    for (int c = 0; c < NC; ++c) {
        size_t o = base + (size_t)c*P_DIM;
        car_re[o] = xre; car_im[o] = xim;
        float sre = sum_re[o], sim = sum_im[o];
        float nr = fmaf(cr, xre, fmaf(-ci, xim, sre));
        float ni = fmaf(cr, xim, fmaf( ci, xre, sim));
        xre = nr; xim = ni;
    }
}

__global__ __launch_bounds__(256) void scan_apply_k(
    bf16* __restrict__ ur, bf16* __restrict__ ui,
    const float* __restrict__ abar,
    const float* __restrict__ car_re, const float* __restrict__ car_im)
{
    int idx = blockIdx.x*256 + threadIdx.x;
    if (idx >= NSCAN) return;
    int p = idx % P_DIM;
    int rest = idx / P_DIM;
    int c = rest % NC, b = rest / NC;
    float ar = abar[p], ai = abar[P_DIM + p];
    size_t co = (size_t)b*NC*P_DIM + (size_t)c*P_DIM + p;
    float xre = car_re[co], xim = car_im[co];
    size_t base = ((size_t)b*LSEQ + (size_t)c*CL)*KP + p;
    for (int i = 0; i < CL; ++i) {
        size_t o = base + (size_t)i*KP;
        float br = __bfloat162float(ur[o]);
        float bi = __bfloat162float(ui[o]);
        float nr = fmaf(ar, xre, fmaf(-ai, xim, br));
        float ni = fmaf(ar, xim, fmaf( ai, xre, bi));
        xre = nr; xim = ni;
        ur[o] = __float2bfloat16(xre);
        ui[o] = __float2bfloat16(xim);
    }
}

// ---------------- head ----------------
__global__ void head_init_k(float* out, const float* hb)
{
    if (threadIdx.x < BSZ) out[threadIdx.x] = hb[0];
}

__global__ __launch_bounds__(256) void head_k(
    const float* __restrict__ h, const float* __restrict__ hw,
    float* __restrict__ out)
{
    int b = blockIdx.x;
    int chunk = blockIdx.y;
    const float* hb = h + ((size_t)b*LSEQ + (size_t)chunk*64)*D_MODEL;
    float s = 0.f;
    for (int l = 0; l < 64; ++l) {
        const float* hr = hb + (size_t)l*D_MODEL;
        for (int d = threadIdx.x; d < D_MODEL; d += 256)
            s += hr[d]*hw[d];
    }
    for (int off = 32; off; off >>= 1) s += __shfl_down(s, off, 64);
    __shared__ float sm[4];
    int lane = threadIdx.x & 63, wv = threadIdx.x >> 6;
    if (lane == 0) sm[wv] = s;
    __syncthreads();
    if (threadIdx.x == 0)
        atomicAdd(out + b, (sm[0]+sm[1]+sm[2]+sm[3]) * (1.f/LSEQ));
}

// ---------------- launch ----------------
extern "C" void kernel_launch(void* const* d_in, const int* in_sizes, int n_in,
                              void* d_out, int out_size, void* d_ws, size_t ws_size,
                              hipStream_t stream)
{
    const float* x          = (const float*)d_in[0];
    const float* enc_w      = (const float*)d_in[1];
    const float* enc_b      = (const float*)d_in[2];
    const float* norm_w     = (const float*)d_in[3];
    const float* norm_b     = (const float*)d_in[4];
    const float* attn_w     = (const float*)d_in[5];
    const float* attn_b     = (const float*)d_in[6];
    const float* ff_w       = (const float*)d_in[7];
    const float* ff_b       = (const float*)d_in[8];
    const float* lam_re     = (const float*)d_in[9];
    const float* lam_im     = (const float*)d_in[10];
    const float* log_step   = (const float*)d_in[11];
    const float* B_re       = (const float*)d_in[12];
    const float* B_im       = (const float*)d_in[13];
    const float* C_re       = (const float*)d_in[14];
    const float* C_im       = (const float*)d_in[15];
    const float* Dvec       = (const float*)d_in[16];
    const float* Wenc       = (const float*)d_in[17];
    const float* Wdec       = (const float*)d_in[18];
    const float* head_w     = (const float*)d_in[19];
    const float* head_b     = (const float*)d_in[20];
    float* out = (float*)d_out;

    // ---- workspace (~233 MB) ----
    float* h    = (float*)d_ws;            // BLD fp32
    bf16*  b1   = (bf16*)(h + BLD);        // BLA bf16 each
    bf16*  b2   = b1 + BLA;
    bf16*  b3   = b2 + BLA;
    bf16*  b4   = b3 + BLA;
    bf16*  wbr  = b4 + BLA;                // Bbar re/im
    bf16*  wbi  = wbr + NPKP;
    bf16*  w5   = wbi + NPKP;              // wcr,wci(-),wea,weg,wd contiguous
    bf16*  wcr  = w5;
    bf16*  wci  = w5 + NPKP;
    bf16*  wea  = w5 + 2*NPKP;
    bf16*  weg  = w5 + 3*NPKP;
    bf16*  wd   = w5 + 4*NPKP;
    float* abar = (float*)(w5 + 5*NPKP);   // 2*P fp32
    float* sum_re = abar + 2*P_DIM;
    float* sum_im = sum_re + NSCAN;
    float* car_re = sum_im + NSCAN;
    float* car_im = car_re + NSCAN;

    const int EW_U = (int)((BLD + 255)/256);
    const int CV   = (int)((NPKP + 255)/256);
    const int SC_G = (NSCAN + 255)/256;
    const size_t pd = (size_t)P_DIM*D_MODEL;

    encode_k<<<EW_U, 256, 0, stream>>>(x, enc_w, enc_b, h);

    for (int i = 0; i < NLAYER; ++i) {
        prep_k<<<CV, 256, 0, stream>>>(
            lam_re + i*P_DIM, lam_im + i*P_DIM, log_step + i*P_DIM,
            B_re + i*pd, B_im + i*pd, wbr, wbi, abar);
        const float* WencA = Wenc + (size_t)i*2*pd;
        const float* WencG = WencA + pd;
        convw5_k<<<dim3(CV,1,5), 256, 0, stream>>>(
            C_re + i*pd, C_im + i*pd, WencA, WencG, Wdec + i*pd, w5);

        // fx = LN(LN(h)) in one pass
        ln2x_k<<<BL, 256, 0, stream>>>(h, norm_w + i*D_MODEL, norm_b + i*D_MODEL,
                                       attn_w + i*D_MODEL, attn_b + i*D_MODEL, b2);

        // Bu_re, Bu_im in one dual-output GEMM
        gemm2o_k<0><<<NGEMM, 256, 0, stream>>>(b2, wbr, wbi, b1, b3, P_DIM);

        // chunked parallel scan (in-place on b1/b3)
        scan_partial_k<<<SC_G, 256, 0, stream>>>(b1, b3, abar, sum_re, sum_im);
        scan_carry_k<<<(BSZ*P_DIM + 255)/256, 256, 0, stream>>>(sum_re, sum_im, abar, car_re, car_im);
        scan_apply_k<<<SC_G, 256, 0, stream>>>(b1, b3, abar, car_re, car_im);

        // z2 = gelu(xs_re@C_re^T + xs_im@(-C_im)^T + Dvec*fx) + fx
        gemmC_k<<<NGEMM, 256, 0, stream>>>(b1, wcr, b3, wci, b2, Dvec + i*D_MODEL, b4, D_MODEL);

        // fy = LN(z2)
        ln_k<<<BL, 256, 0, stream>>>(b4, ff_w + i*D_MODEL, ff_b + i*D_MODEL, b1);

        // GEGLU MLP: b2 = (fy@WencA^T) * gelu(fy@WencG^T)
        gemm2o_k<1><<<NGEMM, 256, 0, stream>>>(b1, wea, weg, b2, nullptr, D_MODEL);

        // h += b2@Wdec^T + fy
        gemmD_k<<<NGEMM, 256, 0, stream>>>(b2, wd, b1, h, D_MODEL);
    }

    head_init_k<<<1, 64, 0, stream>>>(out, head_b);
    head_k<<<dim3(BSZ, 64), 256, 0, stream>>>(h, head_w, out);
}

// Round 10
// 2098.802 us; speedup vs baseline: 1.4028x; 1.4028x over previous
//
#include <hip/hip_runtime.h>
#include <hip/hip_bf16.h>
#include <cstddef>

typedef __hip_bfloat16 bf16;

// ---------------- problem constants ----------------
#define D_MODEL 1048
#define P_DIM   1048
#define NLAYER  3
#define BSZ     4
#define LSEQ    4096
#define BL      (BSZ*LSEQ)                 // 16384 rows
#define BLD     ((size_t)BL*D_MODEL)       // unpadded elements
#define KP      1056                       // padded K / row stride (33*32)
#define NP      1152                       // padded N for weights (9*128)
#define BLA     ((size_t)BL*KP)            // padded activation elements
#define NPKP    ((size_t)NP*KP)            // padded weight elements

// scan chunking
#define NC      64
#define CL      (LSEQ/NC)                  // 64
#define NSCAN   (BSZ*NC*P_DIM)
#define P2      (P_DIM/2)                  // 524 pairs
#define NSCAN2  (BSZ*NC*P2)

typedef __attribute__((ext_vector_type(8))) short short8;
typedef __attribute__((ext_vector_type(4))) float f32x4;

#define TM 128
#define TN 128
#define TK 32
#define TILE_SH (TM*TK)                    // 4096 shorts = 8 KB per sub-tile
#define NGEMM   ((BL/TM)*(NP/TN))          // 1152 blocks

__device__ __forceinline__ float gelu_f(float x) {
    return 0.5f * x * (1.f + erff(x * 0.70710678118654752f));
}

// XCD-aware mapping (1152 blocks): 9 consecutive blocks on one XCD share an
// A m-tile (xcd = blockId % 8 round-robin).
__device__ __forceinline__ void tile_coords(int id, int& m0, int& n0) {
    int xcd  = id & 7;
    int slot = id >> 3;          // 0..143
    int xg   = slot / 9;         // 0..15
    int j    = slot - xg*9;      // 0..8
    m0 = (xg*8 + xcd) * TM;
    n0 = j * TN;
}

// ---------------- staging: one 128x32 bf16 tile via global_load_lds --------
__device__ __forceinline__ void stage_tile(
    const bf16* __restrict__ src, int row0, int k0, short* lds, int tid)
{
#pragma unroll
    for (int c = 0; c < 2; ++c) {
        int chunk = tid + 256*c;          // 0..511
        int r = chunk >> 2;
        int col = (chunk & 3) * 8;
        __builtin_amdgcn_global_load_lds(
            (const __attribute__((address_space(1))) void*)(src + (size_t)(row0 + r)*KP + k0 + col),
            (__attribute__((address_space(3))) void*)(lds + chunk*8), 16, 0, 0);
    }
}

// ---------------- MFMA sub-steps (one TK=32 slice) ----------------
__device__ __forceinline__ void mfma_step1(
    const short* As, const short* Ws, f32x4 (&acc)[4][4],
    int wm, int wn, int row_in, int quad)
{
    short8 a[4], b[4];
#pragma unroll
    for (int i = 0; i < 4; ++i) {
        a[i] = *(const short8*)&As[(wm + i*16 + row_in)*TK + quad*8];
        b[i] = *(const short8*)&Ws[(wn + i*16 + row_in)*TK + quad*8];
    }
#pragma unroll
    for (int i = 0; i < 4; ++i)
#pragma unroll
        for (int j = 0; j < 4; ++j)
            acc[i][j] = __builtin_amdgcn_mfma_f32_16x16x32_bf16(a[i], b[j], acc[i][j], 0, 0, 0);
}

__device__ __forceinline__ void mfma_step2(
    const short* As, const short* W0s, const short* W1s,
    f32x4 (&acc0)[4][4], f32x4 (&acc1)[4][4],
    int wm, int wn, int row_in, int quad)
{
    short8 a[4], b0[4], b1[4];
#pragma unroll
    for (int i = 0; i < 4; ++i) {
        a[i]  = *(const short8*)&As [(wm + i*16 + row_in)*TK + quad*8];
        b0[i] = *(const short8*)&W0s[(wn + i*16 + row_in)*TK + quad*8];
        b1[i] = *(const short8*)&W1s[(wn + i*16 + row_in)*TK + quad*8];
    }
#pragma unroll
    for (int i = 0; i < 4; ++i)
#pragma unroll
        for (int j = 0; j < 4; ++j) {
            acc0[i][j] = __builtin_amdgcn_mfma_f32_16x16x32_bf16(a[i], b0[j], acc0[i][j], 0, 0, 0);
            acc1[i][j] = __builtin_amdgcn_mfma_f32_16x16x32_bf16(a[i], b1[j], acc1[i][j], 0, 0, 0);
        }
}

// ---------------- dual-output GEMM: acc0 = A@W0^T, acc1 = A@W1^T ------------
// MODE 0: store both (pads zeroed).  MODE 1: O0 = acc0 * gelu(acc1).
// BK=64: two TK=32 sub-tiles per barrier pair; tail iter covers k=1024..1055.
template <int MODE>
__global__ __launch_bounds__(256, 2) void gemm2o_k(
    const bf16* __restrict__ A, const bf16* __restrict__ W0,
    const bf16* __restrict__ W1,
    bf16* __restrict__ O0, bf16* __restrict__ O1, int N)
{
    __shared__ short As[2*TILE_SH];
    __shared__ short W0s[2*TILE_SH];
    __shared__ short W1s[2*TILE_SH];
    const int tid  = threadIdx.x;
    int m0, n0;
    tile_coords(blockIdx.x, m0, n0);
    const int wave = tid >> 6, lane = tid & 63;
    const int wm = (wave >> 1) * 64, wn = (wave & 1) * 64;
    const int row_in = lane & 15, quad = lane >> 4;

    f32x4 acc0[4][4] = {};
    f32x4 acc1[4][4] = {};

    for (int kt = 0; kt < 16; ++kt) {
        const int k0 = kt*64;
        stage_tile(A,  m0, k0,      As,            tid);
        stage_tile(A,  m0, k0 + 32, As + TILE_SH,  tid);
        stage_tile(W0, n0, k0,      W0s,           tid);
        stage_tile(W0, n0, k0 + 32, W0s + TILE_SH, tid);
        stage_tile(W1, n0, k0,      W1s,           tid);
        stage_tile(W1, n0, k0 + 32, W1s + TILE_SH, tid);
        __syncthreads();
        mfma_step2(As,           W0s,           W1s,           acc0, acc1, wm, wn, row_in, quad);
        mfma_step2(As + TILE_SH, W0s + TILE_SH, W1s + TILE_SH, acc0, acc1, wm, wn, row_in, quad);
        __syncthreads();
    }
    // tail: k = 1024..1055
    stage_tile(A,  m0, 1024, As,  tid);
    stage_tile(W0, n0, 1024, W0s, tid);
    stage_tile(W1, n0, 1024, W1s, tid);
    __syncthreads();
    mfma_step2(As, W0s, W1s, acc0, acc1, wm, wn, row_in, quad);

#pragma unroll
    for (int i = 0; i < 4; ++i) {
#pragma unroll
        for (int j = 0; j < 4; ++j) {
            int n = n0 + wn + j*16 + row_in;
#pragma unroll
            for (int r = 0; r < 4; ++r) {
                int m = m0 + wm + i*16 + quad*4 + r;
                size_t o = (size_t)m*KP + n;
                if (MODE == 0) {
                    if (n < N)        { O0[o] = __float2bfloat16(acc0[i][j][r]);
                                        O1[o] = __float2bfloat16(acc1[i][j][r]); }
                    else if (n < KP)  { O0[o] = __float2bfloat16(0.f);
                                        O1[o] = __float2bfloat16(0.f); }
                } else {
                    if (n < N)        O0[o] = __float2bfloat16(acc0[i][j][r] * gelu_f(acc1[i][j][r]));
                    else if (n < KP)  O0[o] = __float2bfloat16(0.f);
                }
            }
        }
    }
}

// ---------------- dual-input GEMM + sepi epilogue ----------------
// acc = A0@W0^T + A1@W1^T;  O = gelu(acc + dv[n]*fx) + fx   (pads zeroed)
__global__ __launch_bounds__(256) void gemmC_k(
    const bf16* __restrict__ A0, const bf16* __restrict__ W0,
    const bf16* __restrict__ A1, const bf16* __restrict__ W1,
    const bf16* __restrict__ fx, const float* __restrict__ dv,
    bf16* __restrict__ O, int N)
{
    __shared__ short As[2*TILE_SH];
    __shared__ short Ws[2*TILE_SH];
    const int tid  = threadIdx.x;
    int m0, n0;
    tile_coords(blockIdx.x, m0, n0);
    const int wave = tid >> 6, lane = tid & 63;
    const int wm = (wave >> 1) * 64, wn = (wave & 1) * 64;
    const int row_in = lane & 15, quad = lane >> 4;

    f32x4 acc[4][4] = {};

    for (int pair = 0; pair < 2; ++pair) {
        const bf16* A = pair ? A1 : A0;
        const bf16* W = pair ? W1 : W0;
        for (int kt = 0; kt < 16; ++kt) {
            const int k0 = kt*64;
            stage_tile(A, m0, k0,      As,           tid);
            stage_tile(A, m0, k0 + 32, As + TILE_SH, tid);
            stage_tile(W, n0, k0,      Ws,           tid);
            stage_tile(W, n0, k0 + 32, Ws + TILE_SH, tid);
            __syncthreads();
            mfma_step1(As,           Ws,           acc, wm, wn, row_in, quad);
            mfma_step1(As + TILE_SH, Ws + TILE_SH, acc, wm, wn, row_in, quad);
            __syncthreads();
        }
        stage_tile(A, m0, 1024, As, tid);
        stage_tile(W, n0, 1024, Ws, tid);
        __syncthreads();
        mfma_step1(As, Ws, acc, wm, wn, row_in, quad);
        __syncthreads();
    }

#pragma unroll
    for (int i = 0; i < 4; ++i) {
#pragma unroll
        for (int j = 0; j < 4; ++j) {
            int n = n0 + wn + j*16 + row_in;
#pragma unroll
            for (int r = 0; r < 4; ++r) {
                int m = m0 + wm + i*16 + quad*4 + r;
                size_t o = (size_t)m*KP + n;
                if (n < N) {
                    float f = __bfloat162float(fx[o]);
                    float t = acc[i][j][r] + dv[n]*f;
                    O[o] = __float2bfloat16(gelu_f(t) + f);
                } else if (n < KP) {
                    O[o] = __float2bfloat16(0.f);
                }
            }
        }
    }
}

// ---------------- single GEMM + residual epilogue: h += acc + fy -----------
__global__ __launch_bounds__(256) void gemmD_k(
    const bf16* __restrict__ A, const bf16* __restrict__ W,
    const bf16* __restrict__ fy, float* __restrict__ h, int N)
{
    __shared__ short As[2*TILE_SH];
    __shared__ short Ws[2*TILE_SH];
    const int tid  = threadIdx.x;
    int m0, n0;
    tile_coords(blockIdx.x, m0, n0);
    const int wave = tid >> 6, lane = tid & 63;
    const int wm = (wave >> 1) * 64, wn = (wave & 1) * 64;
    const int row_in = lane & 15, quad = lane >> 4;

    f32x4 acc[4][4] = {};

    for (int kt = 0; kt < 16; ++kt) {
        const int k0 = kt*64;
        stage_tile(A, m0, k0,      As,           tid);
        stage_tile(A, m0, k0 + 32, As + TILE_SH, tid);
        stage_tile(W, n0, k0,      Ws,           tid);
        stage_tile(W, n0, k0 + 32, Ws + TILE_SH, tid);
        __syncthreads();
        mfma_step1(As,           Ws,           acc, wm, wn, row_in, quad);
        mfma_step1(As + TILE_SH, Ws + TILE_SH, acc, wm, wn, row_in, quad);
        __syncthreads();
    }
    stage_tile(A, m0, 1024, As, tid);
    stage_tile(W, n0, 1024, Ws, tid);
    __syncthreads();
    mfma_step1(As, Ws, acc, wm, wn, row_in, quad);

#pragma unroll
    for (int i = 0; i < 4; ++i) {
#pragma unroll
        for (int j = 0; j < 4; ++j) {
            int n = n0 + wn + j*16 + row_in;
            if (n >= N) continue;
#pragma unroll
            for (int r = 0; r < 4; ++r) {
                int m = m0 + wm + i*16 + quad*4 + r;
                float f = __bfloat162float(fy[(size_t)m*KP + n]);
                h[(size_t)m*D_MODEL + n] += acc[i][j][r] + f;
            }
        }
    }
}

// ---------------- batched weight conversion (5x 1048x1048 fp32 -> bf16) ----
__global__ __launch_bounds__(256) void convw5_k(
    const float* __restrict__ s0, const float* __restrict__ s1,
    const float* __restrict__ s2, const float* __restrict__ s3,
    const float* __restrict__ s4, bf16* __restrict__ dst)
{
    size_t i = (size_t)blockIdx.x*256 + threadIdx.x;
    if (i >= NPKP) return;
    int z = blockIdx.z;
    const float* src = (z == 0) ? s0 : (z == 1) ? s1 : (z == 2) ? s2 : (z == 3) ? s3 : s4;
    float scale = (z == 1) ? -1.f : 1.f;
    int n = (int)(i / KP), k = (int)(i - (size_t)n*KP);
    float v = (n < D_MODEL && k < D_MODEL) ? scale*src[(size_t)n*D_MODEL + k] : 0.f;
    dst[(size_t)z*NPKP + i] = __float2bfloat16(v);
}

// ---------------- reductions ----------------
__device__ __forceinline__ float2 block_reduce2(float a, float b) {
    __syncthreads();   // safe for repeated calls (shared reuse)
    for (int off = 32; off; off >>= 1) {
        a += __shfl_down(a, off, 64);
        b += __shfl_down(b, off, 64);
    }
    __shared__ float sa[4], sb[4];
    int lane = threadIdx.x & 63, wv = threadIdx.x >> 6;
    if (lane == 0) { sa[wv] = a; sb[wv] = b; }
    __syncthreads();
    if (threadIdx.x == 0) {
        sa[0] = sa[0]+sa[1]+sa[2]+sa[3];
        sb[0] = sb[0]+sb[1]+sb[2]+sb[3];
    }
    __syncthreads();
    return make_float2(sa[0], sb[0]);
}

// ---------------- fused double layernorm: fx = LN(LN(h,w1,b1),w2,b2) -------
// ENC=1: additionally computes h = x[row]*ew + eb itself and writes it (layer 0).
template <int ENC>
__global__ __launch_bounds__(256) void ln2x_k(
    const float* __restrict__ xin,
    const float* __restrict__ ew, const float* __restrict__ eb,
    float* __restrict__ hbuf,
    const float* __restrict__ w1, const float* __restrict__ bb1,
    const float* __restrict__ w2, const float* __restrict__ bb2,
    bf16* __restrict__ y)
{
    const size_t row = blockIdx.x;
    float v[5];
    float s = 0.f, ss = 0.f;
    int i = 0;
    if (ENC) {
        float xv = xin[row];
        float* hr = hbuf + row * D_MODEL;
        for (int d = threadIdx.x; d < KP; d += 256, ++i) {
            float t = 0.f;
            if (d < D_MODEL) { t = xv*ew[d] + eb[d]; hr[d] = t; }
            v[i] = t; s += t; ss += t*t;
        }
    } else {
        const float* xr = hbuf + row * D_MODEL;
        for (int d = threadIdx.x; d < KP; d += 256, ++i) {
            float t = (d < D_MODEL) ? xr[d] : 0.f;
            v[i] = t; s += t; ss += t*t;
        }
    }
    float2 r = block_reduce2(s, ss);
    float mu  = r.x * (1.f/D_MODEL);
    float var = r.y * (1.f/D_MODEL) - mu*mu;
    float inv = rsqrtf(var + 1e-5f);
    s = 0.f; ss = 0.f; i = 0;
    for (int d = threadIdx.x; d < KP; d += 256, ++i) {
        float z = (d < D_MODEL) ? (v[i]-mu)*inv*w1[d] + bb1[d] : 0.f;
        v[i] = z; s += z; ss += z*z;
    }
    r = block_reduce2(s, ss);
    mu  = r.x * (1.f/D_MODEL);
    var = r.y * (1.f/D_MODEL) - mu*mu;
    inv = rsqrtf(var + 1e-5f);
    bf16* yr = y + row * KP;
    i = 0;
    for (int d = threadIdx.x; d < KP; d += 256, ++i) {
        float o = (d < D_MODEL) ? (v[i]-mu)*inv*w2[d] + bb2[d] : 0.f;
        yr[d] = __float2bfloat16(o);
    }
}

// ---------------- single layernorm (bf16 in stride KP) ----------------
__global__ __launch_bounds__(256) void ln_k(
    const bf16* __restrict__ x, const float* __restrict__ w,
    const float* __restrict__ b, bf16* __restrict__ y)
{
    const size_t row = blockIdx.x;
    const bf16* xr = x + row * KP;
    float v[5];
    float s = 0.f, ss = 0.f;
    int i = 0;
    for (int d = threadIdx.x; d < KP; d += 256, ++i) {
        float t = (d < D_MODEL) ? __bfloat162float(xr[d]) : 0.f;
        v[i] = t; s += t; ss += t*t;
    }
    float2 r = block_reduce2(s, ss);
    float mu  = r.x * (1.f/D_MODEL);
    float var = r.y * (1.f/D_MODEL) - mu*mu;
    float inv = rsqrtf(var + 1e-5f);
    bf16* yr = y + row * KP;
    i = 0;
    for (int d = threadIdx.x; d < KP; d += 256, ++i) {
        float o = (d < D_MODEL) ? (v[i]-mu)*inv*w[d] + b[d] : 0.f;
        yr[d] = __float2bfloat16(o);
    }
}

// ---------------- per-layer SSM precompute (padded Bbar) ----------------
__global__ __launch_bounds__(256) void prep_k(
    const float* __restrict__ lam_re, const float* __restrict__ lam_im,
    const float* __restrict__ log_step,
    const float* __restrict__ B_re, const float* __restrict__ B_im,
    bf16* __restrict__ bbar_re, bf16* __restrict__ bbar_im,
    float* __restrict__ abar)
{
    size_t idx = (size_t)blockIdx.x*256 + threadIdx.x;
    if (idx >= NPKP) return;
    int p = (int)(idx / KP);
    int d = (int)(idx - (size_t)p*KP);
    if (p >= P_DIM || d >= D_MODEL) {
        bbar_re[idx] = __float2bfloat16(0.f);
        bbar_im[idx] = __float2bfloat16(0.f);
        return;
    }
    float lr = lam_re[p], li = lam_im[p];
    float st = expf(log_step[p]);
    float er = expf(lr*st);
    float ar = er * cosf(li*st);
    float ai = er * sinf(li*st);
    if (d == 0) { abar[p] = ar; abar[P_DIM + p] = ai; }
    float den = lr*lr + li*li;
    float xr = ar - 1.f, xi = ai;
    float cr = (xr*lr + xi*li) / den;
    float ci = (xi*lr - xr*li) / den;
    float br = B_re[(size_t)p*D_MODEL + d], bi = B_im[(size_t)p*D_MODEL + d];
    bbar_re[idx] = __float2bfloat16(cr*br - ci*bi);
    bbar_im[idx] = __float2bfloat16(cr*bi + ci*br);
}

// ---------------- chunked parallel scan (2 p per thread, ushort2) ----------
__device__ __forceinline__ float2 bf2f(unsigned int u) {
    unsigned int lo = u << 16, hi = u & 0xffff0000u;
    float2 r;
    r.x = __uint_as_float(lo);
    r.y = __uint_as_float(hi);
    return r;
}
__device__ __forceinline__ unsigned int f2bf2(float a, float b) {
    bf16 ba = __float2bfloat16(a), bb = __float2bfloat16(b);
    unsigned short ua = *(unsigned short*)&ba, ub = *(unsigned short*)&bb;
    return (unsigned int)ua | ((unsigned int)ub << 16);
}

__global__ __launch_bounds__(256) void scan_partial_k(
    const unsigned int* __restrict__ ur, const unsigned int* __restrict__ ui,
    const float* __restrict__ abar,
    float* __restrict__ sum_re, float* __restrict__ sum_im)
{
    int idx = blockIdx.x*256 + threadIdx.x;
    if (idx >= NSCAN2) return;
    int p2 = idx % P2;
    int rest = idx / P2;
    int c = rest % NC, b = rest / NC;
    int p = 2*p2;
    float ar0 = abar[p],   ai0 = abar[P_DIM + p];
    float ar1 = abar[p+1], ai1 = abar[P_DIM + p + 1];
    size_t base = (((size_t)b*LSEQ + (size_t)c*CL)*KP + p) >> 1;   // u32 index
    float s0r = 0.f, s0i = 0.f, s1r = 0.f, s1i = 0.f;
    for (int i = 0; i < CL; ++i) {
        size_t o = base + (size_t)i*(KP/2);
        float2 br = bf2f(ur[o]);
        float2 bi = bf2f(ui[o]);
        float n0r = fmaf(ar0, s0r, fmaf(-ai0, s0i, br.x));
        float n0i = fmaf(ar0, s0i, fmaf( ai0, s0r, bi.x));
        float n1r = fmaf(ar1, s1r, fmaf(-ai1, s1i, br.y));
        float n1i = fmaf(ar1, s1i, fmaf( ai1, s1r, bi.y));
        s0r = n0r; s0i = n0i; s1r = n1r; s1i = n1i;
    }
    size_t so = ((size_t)b*NC + c)*P_DIM + p;
    *(float2*)&sum_re[so] = make_float2(s0r, s1r);
    *(float2*)&sum_im[so] = make_float2(s0i, s1i);
}

__global__ __launch_bounds__(256) void scan_carry_k(
    const float* __restrict__ sum_re, const float* __restrict__ sum_im,
    const float* __restrict__ abar,
    float* __restrict__ car_re, float* __restrict__ car_im)
{
    int idx = blockIdx.x*256 + threadIdx.x;
    if (idx >= BSZ*P_DIM) return;
    int p = idx % P_DIM, b = idx / P_DIM;
    float cr = abar[p], ci = abar[P_DIM + p];
#pragma unroll
    for (int s = 0; s < 6; ++s) {       // a^64 by repeated squaring
        float nr = cr*cr - ci*ci;
        float ni = 2.f*cr*ci;
        cr = nr; ci = ni;
    }
    float xre = 0.f, xim = 0.f;
    size_t base = (size_t)b*NC*P_DIM + p;
    for (int c = 0; c < NC; ++c) {
        size_t o = base + (size_t)c*P_DIM;
        car_re[o] = xre; car_im[o] = xim;
        float sre = sum_re[o], sim = sum_im[o];
        float nr = fmaf(cr, xre, fmaf(-ci, xim, sre));
        float ni = fmaf(cr, xim, fmaf( ci, xre, sim));
        xre = nr; xim = ni;
    }
}

__global__ __launch_bounds__(256) void scan_apply_k(
    unsigned int* __restrict__ ur, unsigned int* __restrict__ ui,
    const float* __restrict__ abar,
    const float* __restrict__ car_re, const float* __restrict__ car_im)
{
    int idx = blockIdx.x*256 + threadIdx.x;
    if (idx >= NSCAN2) return;
    int p2 = idx % P2;
    int rest = idx / P2;
    int c = rest % NC, b = rest / NC;
    int p = 2*p2;
    float ar0 = abar[p],   ai0 = abar[P_DIM + p];
    float ar1 = abar[p+1], ai1 = abar[P_DIM + p + 1];
    size_t co = ((size_t)b*NC + c)*P_DIM + p;
    float2 c_r = *(const float2*)&car_re[co];
    float2 c_i = *(const float2*)&car_im[co];
    float x0r = c_r.x, x0i = c_i.x, x1r = c_r.y, x1i = c_i.y;
    size_t base = (((size_t)b*LSEQ + (size_t)c*CL)*KP + p) >> 1;
    for (int i = 0; i < CL; ++i) {
        size_t o = base + (size_t)i*(KP/2);
        float2 br = bf2f(ur[o]);
        float2 bi = bf2f(ui[o]);
        float n0r = fmaf(ar0, x0r, fmaf(-ai0, x0i, br.x));
        float n0i = fmaf(ar0, x0i, fmaf( ai0, x0r, bi.x));
        float n1r = fmaf(ar1, x1r, fmaf(-ai1, x1i, br.y));
        float n1i = fmaf(ar1, x1i, fmaf( ai1, x1r, bi.y));
        x0r = n0r; x0i = n0i; x1r = n1r; x1i = n1i;
        ur[o] = f2bf2(x0r, x1r);
        ui[o] = f2bf2(x0i, x1i);
    }
}

// ---------------- head ----------------
__global__ void head_init_k(float* out, const float* hb)
{
    if (threadIdx.x < BSZ) out[threadIdx.x] = hb[0];
}

__global__ __launch_bounds__(256) void head_k(
    const float* __restrict__ h, const float* __restrict__ hw,
    float* __restrict__ out)
{
    int b = blockIdx.x;
    int chunk = blockIdx.y;
    const float* hb = h + ((size_t)b*LSEQ + (size_t)chunk*64)*D_MODEL;
    float s = 0.f;
    for (int l = 0; l < 64; ++l) {
        const float* hr = hb + (size_t)l*D_MODEL;
        for (int d = threadIdx.x; d < D_MODEL; d += 256)
            s += hr[d]*hw[d];
    }
    for (int off = 32; off; off >>= 1) s += __shfl_down(s, off, 64);
    __shared__ float sm[4];
    int lane = threadIdx.x & 63, wv = threadIdx.x >> 6;
    if (lane == 0) sm[wv] = s;
    __syncthreads();
    if (threadIdx.x == 0)
        atomicAdd(out + b, (sm[0]+sm[1]+sm[2]+sm[3]) * (1.f/LSEQ));
}

// ---------------- launch ----------------
extern "C" void kernel_launch(void* const* d_in, const int* in_sizes, int n_in,
                              void* d_out, int out_size, void* d_ws, size_t ws_size,
                              hipStream_t stream)
{
    const float* x          = (const float*)d_in[0];
    const float* enc_w      = (const float*)d_in[1];
    const float* enc_b      = (const float*)d_in[2];
    const float* norm_w     = (const float*)d_in[3];
    const float* norm_b     = (const float*)d_in[4];
    const float* attn_w     = (const float*)d_in[5];
    const float* attn_b     = (const float*)d_in[6];
    const float* ff_w       = (const float*)d_in[7];
    const float* ff_b       = (const float*)d_in[8];
    const float* lam_re     = (const float*)d_in[9];
    const float* lam_im     = (const float*)d_in[10];
    const float* log_step   = (const float*)d_in[11];
    const float* B_re       = (const float*)d_in[12];
    const float* B_im       = (const float*)d_in[13];
    const float* C_re       = (const float*)d_in[14];
    const float* C_im       = (const float*)d_in[15];
    const float* Dvec       = (const float*)d_in[16];
    const float* Wenc       = (const float*)d_in[17];
    const float* Wdec       = (const float*)d_in[18];
    const float* head_w     = (const float*)d_in[19];
    const float* head_b     = (const float*)d_in[20];
    float* out = (float*)d_out;

    // ---- workspace (~233 MB) ----
    float* h    = (float*)d_ws;            // BLD fp32
    bf16*  b1   = (bf16*)(h + BLD);        // BLA bf16 each
    bf16*  b2   = b1 + BLA;
    bf16*  b3   = b2 + BLA;
    bf16*  b4   = b3 + BLA;
    bf16*  wbr  = b4 + BLA;                // Bbar re/im
    bf16*  wbi  = wbr + NPKP;
    bf16*  w5   = wbi + NPKP;              // wcr,wci(-),wea,weg,wd contiguous
    bf16*  wcr  = w5;
    bf16*  wci  = w5 + NPKP;
    bf16*  wea  = w5 + 2*NPKP;
    bf16*  weg  = w5 + 3*NPKP;
    bf16*  wd   = w5 + 4*NPKP;
    float* abar = (float*)(w5 + 5*NPKP);   // 2*P fp32
    float* sum_re = abar + 2*P_DIM;
    float* sum_im = sum_re + NSCAN;
    float* car_re = sum_im + NSCAN;
    float* car_im = car_re + NSCAN;

    const int CV   = (int)((NPKP + 255)/256);
    const int SC_G = (NSCAN2 + 255)/256;
    const size_t pd = (size_t)P_DIM*D_MODEL;

    for (int i = 0; i < NLAYER; ++i) {
        prep_k<<<CV, 256, 0, stream>>>(
            lam_re + i*P_DIM, lam_im + i*P_DIM, log_step + i*P_DIM,
            B_re + i*pd, B_im + i*pd, wbr, wbi, abar);
        const float* WencA = Wenc + (size_t)i*2*pd;
        const float* WencG = WencA + pd;
        convw5_k<<<dim3(CV,1,5), 256, 0, stream>>>(
            C_re + i*pd, C_im + i*pd, WencA, WencG, Wdec + i*pd, w5);

        // fx = LN(LN(h)); layer 0 computes and writes h = x*ew+eb itself
        if (i == 0)
            ln2x_k<1><<<BL, 256, 0, stream>>>(x, enc_w, enc_b, h,
                norm_w + i*D_MODEL, norm_b + i*D_MODEL,
                attn_w + i*D_MODEL, attn_b + i*D_MODEL, b2);
        else
            ln2x_k<0><<<BL, 256, 0, stream>>>(nullptr, nullptr, nullptr, h,
                norm_w + i*D_MODEL, norm_b + i*D_MODEL,
                attn_w + i*D_MODEL, attn_b + i*D_MODEL, b2);

        // Bu_re, Bu_im in one dual-output GEMM
        gemm2o_k<0><<<NGEMM, 256, 0, stream>>>(b2, wbr, wbi, b1, b3, P_DIM);

        // chunked parallel scan (in-place on b1/b3)
        scan_partial_k<<<SC_G, 256, 0, stream>>>((unsigned int*)b1, (unsigned int*)b3,
                                                 abar, sum_re, sum_im);
        scan_carry_k<<<(BSZ*P_DIM + 255)/256, 256, 0, stream>>>(sum_re, sum_im, abar, car_re, car_im);
        scan_apply_k<<<SC_G, 256, 0, stream>>>((unsigned int*)b1, (unsigned int*)b3,
                                               abar, car_re, car_im);

        // z2 = gelu(xs_re@C_re^T + xs_im@(-C_im)^T + Dvec*fx) + fx
        gemmC_k<<<NGEMM, 256, 0, stream>>>(b1, wcr, b3, wci, b2, Dvec + i*D_MODEL, b4, D_MODEL);

        // fy = LN(z2)
        ln_k<<<BL, 256, 0, stream>>>(b4, ff_w + i*D_MODEL, ff_b + i*D_MODEL, b1);

        // GEGLU MLP: b2 = (fy@WencA^T) * gelu(fy@WencG^T)
        gemm2o_k<1><<<NGEMM, 256, 0, stream>>>(b1, wea, weg, b2, nullptr, D_MODEL);

        // h += b2@Wdec^T + fy
        gemmD_k<<<NGEMM, 256, 0, stream>>>(b2, wd, b1, h, D_MODEL);
    }

    head_init_k<<<1, 64, 0, stream>>>(out, head_b);
    head_k<<<dim3(BSZ, 64), 256, 0, stream>>>(h, head_w, out);
}